// Round 1
// baseline (17936.261 us; speedup 1.0000x reference)
//
#include <hip/hip_runtime.h>
#include <hip/hip_cooperative_groups.h>

namespace cg = cooperative_groups;

#define BB 32
#define TT 512
#define DD 512
#define HH 1024
#define G4 4096   // 4*H

typedef __bf16 bf16x8 __attribute__((ext_vector_type(8)));
typedef float f32x4 __attribute__((ext_vector_type(4)));

__device__ __forceinline__ unsigned short f2b(float f) {
    unsigned u = __builtin_bit_cast(unsigned, f);
    u += 0x7fffu + ((u >> 16) & 1u);
    return (unsigned short)(u >> 16);
}
__device__ __forceinline__ float b2f(unsigned short s) {
    unsigned u = ((unsigned)s) << 16;
    return __builtin_bit_cast(float, u);
}

// ---------- Kernel 1: xp[B*T,4H] = bf16( X[B*T,D] @ Wi[D,4H] ), fp32 accum ----------
__global__ __launch_bounds__(256) void xproj_gemm(const float* __restrict__ X,
                                                  const float* __restrict__ Wi,
                                                  unsigned short* __restrict__ xp)
{
    __shared__ unsigned short As[64][40];   // [m][k], pad 40 (2-way free)
    __shared__ unsigned short Bs[64][40];   // [n][k] transposed
    const int nb = G4 / 64;                 // 64 n-blocks
    const int m0 = (blockIdx.x / nb) * 64;
    const int n0 = (blockIdx.x % nb) * 64;
    const int tid = threadIdx.x;
    const int w = tid >> 6;
    const int lane = tid & 63;
    const int q = lane >> 4;
    const int l16 = lane & 15;
    const int wm = (w >> 1) * 32, wn = (w & 1) * 32;

    const int ar = tid >> 2, ac = (tid & 3) * 8;   // A staging: 8 consec fp32
    const int bk = tid >> 3, bn = (tid & 7) * 8;   // B staging

    f32x4 acc[2][2] = {};

    for (int k0 = 0; k0 < DD; k0 += 32) {
        const float* ap = X + (size_t)(m0 + ar) * DD + k0 + ac;
        float4 a0 = *(const float4*)ap;
        float4 a1 = *(const float4*)(ap + 4);
        unsigned short* as = &As[ar][ac];
        as[0]=f2b(a0.x); as[1]=f2b(a0.y); as[2]=f2b(a0.z); as[3]=f2b(a0.w);
        as[4]=f2b(a1.x); as[5]=f2b(a1.y); as[6]=f2b(a1.z); as[7]=f2b(a1.w);
        const float* bp = Wi + (size_t)(k0 + bk) * G4 + n0 + bn;
        float4 b0 = *(const float4*)bp;
        float4 b1 = *(const float4*)(bp + 4);
        Bs[bn+0][bk]=f2b(b0.x); Bs[bn+1][bk]=f2b(b0.y); Bs[bn+2][bk]=f2b(b0.z); Bs[bn+3][bk]=f2b(b0.w);
        Bs[bn+4][bk]=f2b(b1.x); Bs[bn+5][bk]=f2b(b1.y); Bs[bn+6][bk]=f2b(b1.z); Bs[bn+7][bk]=f2b(b1.w);
        __syncthreads();
        bf16x8 af0 = *(const bf16x8*)&As[wm + l16][q*8];
        bf16x8 af1 = *(const bf16x8*)&As[wm + 16 + l16][q*8];
        bf16x8 bf0 = *(const bf16x8*)&Bs[wn + l16][q*8];
        bf16x8 bf1 = *(const bf16x8*)&Bs[wn + 16 + l16][q*8];
        acc[0][0] = __builtin_amdgcn_mfma_f32_16x16x32_bf16(af0, bf0, acc[0][0], 0,0,0);
        acc[0][1] = __builtin_amdgcn_mfma_f32_16x16x32_bf16(af0, bf1, acc[0][1], 0,0,0);
        acc[1][0] = __builtin_amdgcn_mfma_f32_16x16x32_bf16(af1, bf0, acc[1][0], 0,0,0);
        acc[1][1] = __builtin_amdgcn_mfma_f32_16x16x32_bf16(af1, bf1, acc[1][1], 0,0,0);
        __syncthreads();
    }
    for (int i = 0; i < 2; i++) for (int j = 0; j < 2; j++) {
        int R = m0 + wm + i*16 + q*4;     // C/D: col=lane&15, row=quad*4+reg
        int C = n0 + wn + j*16 + l16;
        for (int r = 0; r < 4; r++)
            xp[(size_t)(R + r) * G4 + C] = f2b(acc[i][j][r]);
    }
}

// ---------- Kernel 2: persistent cooperative LSTM scan ----------
// 256 WGs; WG j owns h-dims [4j,4j+4) -> 16 gate columns of Wh in LDS.
// Per step: gates[32,16] = h[32,1024] @ WhSlice via MFMA (K split over wave pairs),
// fp32 pointwise with c in registers, h double-buffered bf16 in ws, 1 grid sync/step.
#define NWG 256
#define DPW 4

__global__ __launch_bounds__(256, 1) void lstm_seq(
    const unsigned short* __restrict__ xp,
    const int* __restrict__ lengths,
    const float* __restrict__ c0,
    const float* __restrict__ h0,
    const float* __restrict__ Wh,
    const float* __restrict__ bias,
    float* __restrict__ out,              // outputs[B,T,H] | c_fin[B,H] | h_fin[B,H]
    unsigned short* __restrict__ hbuf)    // [2][B*H] bf16
{
    __shared__ unsigned short Wt[16][1032];  // [n_local][k], stride 1032 -> 2-way (free)
    __shared__ float gs[2][32][17];          // [khalf][batch][n_local]
    const int wg = blockIdx.x;
    const int tid = threadIdx.x;
    const int lane = tid & 63;
    const int w = tid >> 6;
    const int q = lane >> 4, l16 = lane & 15;

    // One-time: stage Wh slice (cols gate*H + wg*4 + d) into LDS as bf16, [n][k].
    for (int idx = tid; idx < 16 * HH; idx += 256) {
        int n = idx & 15, k = idx >> 4;
        int col = (n >> 2) * HH + wg * DPW + (n & 3);
        Wt[n][k] = f2b(Wh[(size_t)k * G4 + col]);
    }

    // Per-thread recurrent state (threads 0..127: (batch, dim) pairs)
    const int bb = tid >> 2, dd = tid & 3;
    const int gdim = wg * DPW + dd;
    float c = 0.f;
    int len = -1;
    float bi = 0.f, bfg = 0.f, bg = 0.f, bo = 0.f;
    if (tid < 128) {
        c   = c0[bb * HH + gdim];
        len = lengths[bb];
        bi  = bias[0*HH + gdim];
        bfg = bias[1*HH + gdim];
        bg  = bias[2*HH + gdim];
        bo  = bias[3*HH + gdim];
        hbuf[bb * HH + gdim] = f2b(h0[bb * HH + gdim]);   // buffer 0 init
    }
    cg::this_grid().sync();

    const int Mt = (w & 1) * 16;     // batch tile for this wave
    const int kh = w >> 1;           // K half
    const int kbase = kh * 512;

    for (int t = 0; t < TT; ++t) {
        const unsigned short* hp = hbuf + (t & 1) * (BB * HH);
        f32x4 acc = {0.f, 0.f, 0.f, 0.f};
        #pragma unroll
        for (int kk = 0; kk < 16; ++kk) {
            int k0 = kbase + kk * 32;
            bf16x8 a   = *(const bf16x8*)(hp + (Mt + l16) * HH + k0 + q * 8);  // A[m][k]
            bf16x8 bfr = *(const bf16x8*)&Wt[l16][k0 + q * 8];                 // B[k][n] as [n][k]
            acc = __builtin_amdgcn_mfma_f32_16x16x32_bf16(a, bfr, acc, 0, 0, 0);
        }
        #pragma unroll
        for (int r = 0; r < 4; ++r)
            gs[kh][Mt + q*4 + r][l16] = acc[r];
        __syncthreads();
        if (tid < 128) {
            const unsigned short* xr = xp + ((size_t)bb * TT + t) * G4;
            float gi = gs[0][bb][ 0 + dd] + gs[1][bb][ 0 + dd] + b2f(xr[0*HH + gdim]) + bi;
            float gf = gs[0][bb][ 4 + dd] + gs[1][bb][ 4 + dd] + b2f(xr[1*HH + gdim]) + bfg;
            float gg = gs[0][bb][ 8 + dd] + gs[1][bb][ 8 + dd] + b2f(xr[2*HH + gdim]) + bg;
            float go = gs[0][bb][12 + dd] + gs[1][bb][12 + dd] + b2f(xr[3*HH + gdim]) + bo;
            // numerically stable forms (no inf/inf)
            float si = 1.f / (1.f + __expf(-gi));
            float sf = 1.f / (1.f + __expf(-gf));
            float so = 1.f / (1.f + __expf(-go));
            float tg = 1.f - 2.f / (1.f + __expf(2.f * gg));
            c = sf * c + si * tg;
            float th = 1.f - 2.f / (1.f + __expf(2.f * c));
            float h = so * th;
            out[((size_t)bb * TT + t) * HH + gdim] = h;
            hbuf[((t + 1) & 1) * (BB * HH) + bb * HH + gdim] = f2b(h);
            if (t == len - 1) {
                out[(size_t)BB*TT*HH + bb*HH + gdim] = c;
                out[(size_t)BB*TT*HH + (size_t)BB*HH + bb*HH + gdim] = h;
            }
        }
        cg::this_grid().sync();   // double-buffered h: one sync per step suffices
    }
}

extern "C" void kernel_launch(void* const* d_in, const int* in_sizes, int n_in,
                              void* d_out, int out_size, void* d_ws, size_t ws_size,
                              hipStream_t stream)
{
    const float* X    = (const float*)d_in[0];
    const int*   lens = (const int*)d_in[1];
    const float* c0   = (const float*)d_in[2];
    const float* h0   = (const float*)d_in[3];
    const float* Wi   = (const float*)d_in[4];
    const float* Wh   = (const float*)d_in[5];
    const float* bias = (const float*)d_in[6];
    float* out = (float*)d_out;

    // ws layout: xp bf16 [B*T,4H] (134.2 MB) | hbuf bf16 [2][B*H]
    unsigned short* xp   = (unsigned short*)d_ws;
    unsigned short* hbuf = xp + (size_t)BB * TT * G4;

    xproj_gemm<<<dim3((BB*TT/64) * (G4/64)), dim3(256), 0, stream>>>(X, Wi, xp);

    const unsigned short* xp_c = xp;
    unsigned short* hbuf_p = hbuf;
    void* args[8];
    args[0] = (void*)&xp_c;
    args[1] = (void*)&lens;
    args[2] = (void*)&c0;
    args[3] = (void*)&h0;
    args[4] = (void*)&Wh;
    args[5] = (void*)&bias;
    args[6] = (void*)&out;
    args[7] = (void*)&hbuf_p;
    hipLaunchCooperativeKernel((void*)lstm_seq, dim3(NWG), dim3(256), args, 0, stream);
}

// Round 3
// 10874.144 us; speedup vs baseline: 1.6494x; 1.6494x over previous
//
#include <hip/hip_runtime.h>

#define BB 32
#define TT 512
#define DD 512
#define HH 1024
#define G4 4096   // 4*H
#define NWG 256
#define DPW 4

typedef __bf16 bf16x8 __attribute__((ext_vector_type(8)));
typedef float f32x4 __attribute__((ext_vector_type(4)));
typedef unsigned int u32x4 __attribute__((ext_vector_type(4)));
typedef unsigned short u16x4 __attribute__((ext_vector_type(4)));

__device__ __forceinline__ unsigned short f2b(float f) {
    unsigned u = __builtin_bit_cast(unsigned, f);
    u += 0x7fffu + ((u >> 16) & 1u);
    return (unsigned short)(u >> 16);
}
__device__ __forceinline__ float b2f(unsigned short s) {
    unsigned u = ((unsigned)s) << 16;
    return __builtin_bit_cast(float, u);
}

// ---------- Kernel 1: xp[B][4H][T] = bf16( X[B*T,D] @ Wi[D,4H] ), fp32 accum ----------
__global__ __launch_bounds__(256) void xproj_gemm(const float* __restrict__ X,
                                                  const float* __restrict__ Wi,
                                                  unsigned short* __restrict__ xp)
{
    __shared__ unsigned short As[64][40];   // [m][k]
    __shared__ unsigned short Bs[64][40];   // [n][k] transposed
    const int nb = G4 / 64;
    const int m0 = (blockIdx.x / nb) * 64;
    const int n0 = (blockIdx.x % nb) * 64;
    const int tid = threadIdx.x;
    const int w = tid >> 6;
    const int lane = tid & 63;
    const int q = lane >> 4;
    const int l16 = lane & 15;
    const int wm = (w >> 1) * 32, wn = (w & 1) * 32;

    const int ar = tid >> 2, ac = (tid & 3) * 8;
    const int bk = tid >> 3, bn = (tid & 7) * 8;

    f32x4 acc[2][2] = {};

    for (int k0 = 0; k0 < DD; k0 += 32) {
        const float* ap = X + (size_t)(m0 + ar) * DD + k0 + ac;
        float4 a0 = *(const float4*)ap;
        float4 a1 = *(const float4*)(ap + 4);
        unsigned short* as = &As[ar][ac];
        as[0]=f2b(a0.x); as[1]=f2b(a0.y); as[2]=f2b(a0.z); as[3]=f2b(a0.w);
        as[4]=f2b(a1.x); as[5]=f2b(a1.y); as[6]=f2b(a1.z); as[7]=f2b(a1.w);
        const float* bp = Wi + (size_t)(k0 + bk) * G4 + n0 + bn;
        float4 b0 = *(const float4*)bp;
        float4 b1 = *(const float4*)(bp + 4);
        Bs[bn+0][bk]=f2b(b0.x); Bs[bn+1][bk]=f2b(b0.y); Bs[bn+2][bk]=f2b(b0.z); Bs[bn+3][bk]=f2b(b0.w);
        Bs[bn+4][bk]=f2b(b1.x); Bs[bn+5][bk]=f2b(b1.y); Bs[bn+6][bk]=f2b(b1.z); Bs[bn+7][bk]=f2b(b1.w);
        __syncthreads();
        bf16x8 af0 = *(const bf16x8*)&As[wm + l16][q*8];
        bf16x8 af1 = *(const bf16x8*)&As[wm + 16 + l16][q*8];
        bf16x8 bf0 = *(const bf16x8*)&Bs[wn + l16][q*8];
        bf16x8 bf1 = *(const bf16x8*)&Bs[wn + 16 + l16][q*8];
        acc[0][0] = __builtin_amdgcn_mfma_f32_16x16x32_bf16(af0, bf0, acc[0][0], 0,0,0);
        acc[0][1] = __builtin_amdgcn_mfma_f32_16x16x32_bf16(af0, bf1, acc[0][1], 0,0,0);
        acc[1][0] = __builtin_amdgcn_mfma_f32_16x16x32_bf16(af1, bf0, acc[1][0], 0,0,0);
        acc[1][1] = __builtin_amdgcn_mfma_f32_16x16x32_bf16(af1, bf1, acc[1][1], 0,0,0);
        __syncthreads();
    }
    // C/D: col=lane&15, row=quad*4+reg. Store transposed to xp[b][gcol][t]:
    // rows R..R+3 are 4 consecutive t within one b (tiles are 64-aligned, T=512).
    for (int i = 0; i < 2; i++) for (int j = 0; j < 2; j++) {
        int R = m0 + wm + i*16 + q*4;
        int C = n0 + wn + j*16 + l16;
        int b = R >> 9;
        int t = R & 511;
        u16x4 v;
        v.x = f2b(acc[i][j][0]); v.y = f2b(acc[i][j][1]);
        v.z = f2b(acc[i][j][2]); v.w = f2b(acc[i][j][3]);
        *(u16x4*)(xp + ((size_t)b * G4 + C) * TT + t) = v;
    }
}

// ---------- Kernel 2: persistent LSTM scan, dataflow-flag pipeline (no grid barrier) ----------
// WG j owns h-dims [4j,4j+4) -> 16 gate columns of Wh in LDS.
// flags[t][wg]==1  <=>  WG wg has published its slice of h-state entering step t.
// Safety: a WG reaches step t only after ALL WGs finished step t-1, so the
// 2-slot hbuf double buffer has no WAR hazard (all reads of slot (t-1)&1 are
// complete before any WG can write slot (t+1)&1 == (t-1)&1).
__global__ __launch_bounds__(256, 1) void lstm_seq(
    const unsigned short* __restrict__ xp,      // [B][4H][T] bf16
    const int* __restrict__ lengths,
    const float* __restrict__ c0,
    const float* __restrict__ h0,
    const float* __restrict__ Wh,
    const float* __restrict__ bias,
    float* __restrict__ out,                    // outputs[B,T,H] | c_fin[B,H] | h_fin[B,H]
    unsigned short* __restrict__ hbuf,          // [2][B*H] bf16
    unsigned int* __restrict__ flags)           // [T+1][NWG], zeroed by host memset
{
    __shared__ unsigned short Wt[16][1032];  // [n_local][k], stride 1032 -> 2-way (free)
    __shared__ float gs[2][32][17];          // [khalf][batch][n_local]
    const int wg = blockIdx.x;
    const int tid = threadIdx.x;
    const int lane = tid & 63;
    const int w = tid >> 6;
    const int q = lane >> 4, l16 = lane & 15;

    // One-time: stage Wh slice (cols gate*H + wg*4 + d) into LDS as bf16, [n][k].
    for (int idx = tid; idx < 16 * HH; idx += 256) {
        int n = idx & 15, k = idx >> 4;
        int col = (n >> 2) * HH + wg * DPW + (n & 3);
        Wt[n][k] = f2b(Wh[(size_t)k * G4 + col]);
    }

    const int bb = tid >> 2, dd = tid & 3;
    const int gdim = wg * DPW + dd;
    float c = 0.f;
    int len = -1;
    float bi = 0.f, bfg = 0.f, bgv = 0.f, bo = 0.f;
    size_t xb0 = 0, xb1 = 0, xb2 = 0, xb3 = 0;
    if (tid < 128) {
        c   = c0[bb * HH + gdim];
        len = lengths[bb];
        bi  = bias[0*HH + gdim];
        bfg = bias[1*HH + gdim];
        bgv = bias[2*HH + gdim];
        bo  = bias[3*HH + gdim];
        hbuf[bb * HH + gdim] = f2b(h0[bb * HH + gdim]);   // slot 0 init
        xb0 = ((size_t)bb * G4 + 0*HH + gdim) * TT;
        xb1 = ((size_t)bb * G4 + 1*HH + gdim) * TT;
        xb2 = ((size_t)bb * G4 + 2*HH + gdim) * TT;
        xb3 = ((size_t)bb * G4 + 3*HH + gdim) * TT;
    }
    __syncthreads();                 // all slot-0 stores issued & vmcnt-drained
    if (tid == 0) {
        __builtin_amdgcn_fence(__ATOMIC_RELEASE, "agent");   // flush L2 -> L3
        __hip_atomic_store(&flags[wg], 1u, __ATOMIC_RELAXED, __HIP_MEMORY_SCOPE_AGENT);
    }

    const int Mt = (w & 1) * 16;     // batch tile for this wave
    const int kh = w >> 1;           // K half
    const int kbase = kh * 512;

    for (int t0 = 0; t0 < TT; t0 += 8) {
        // Prefetch 8 steps of x-projection per gate (time-contiguous, nontemporal).
        u32x4 xv0 = {}, xv1 = {}, xv2 = {}, xv3 = {};
        if (tid < 128) {
            xv0 = __builtin_nontemporal_load((const u32x4*)(xp + xb0 + t0));
            xv1 = __builtin_nontemporal_load((const u32x4*)(xp + xb1 + t0));
            xv2 = __builtin_nontemporal_load((const u32x4*)(xp + xb2 + t0));
            xv3 = __builtin_nontemporal_load((const u32x4*)(xp + xb3 + t0));
        }
        #pragma unroll
        for (int dt = 0; dt < 8; ++dt) {
            const int t = t0 + dt;
            // Wait until every producer published h entering step t.
            {
                const unsigned* fl = flags + (size_t)t * NWG;
                unsigned mine;
                do {
                    mine = __hip_atomic_load(&fl[tid], __ATOMIC_RELAXED, __HIP_MEMORY_SCOPE_AGENT);
                } while (!__syncthreads_and((int)(mine != 0)));
                __builtin_amdgcn_fence(__ATOMIC_ACQUIRE, "agent");  // invalidate stale L1/L2
            }
            const unsigned short* hp = hbuf + (t & 1) * (BB * HH);
            f32x4 acc = {0.f, 0.f, 0.f, 0.f};
            #pragma unroll
            for (int kk = 0; kk < 16; ++kk) {
                int k0 = kbase + kk * 32;
                bf16x8 a   = *(const bf16x8*)(hp + (Mt + l16) * HH + k0 + q * 8);
                bf16x8 bfr = *(const bf16x8*)&Wt[l16][k0 + q * 8];
                acc = __builtin_amdgcn_mfma_f32_16x16x32_bf16(a, bfr, acc, 0, 0, 0);
            }
            #pragma unroll
            for (int r = 0; r < 4; ++r)
                gs[kh][Mt + q*4 + r][l16] = acc[r];
            __syncthreads();
            if (tid < 128) {
                const unsigned w0 = ((const unsigned*)&xv0)[dt >> 1];
                const unsigned w1 = ((const unsigned*)&xv1)[dt >> 1];
                const unsigned w2 = ((const unsigned*)&xv2)[dt >> 1];
                const unsigned w3 = ((const unsigned*)&xv3)[dt >> 1];
                const int sh = (dt & 1) * 16;
                float gi = gs[0][bb][ 0 + dd] + gs[1][bb][ 0 + dd] + b2f((unsigned short)(w0 >> sh)) + bi;
                float gf = gs[0][bb][ 4 + dd] + gs[1][bb][ 4 + dd] + b2f((unsigned short)(w1 >> sh)) + bfg;
                float gg = gs[0][bb][ 8 + dd] + gs[1][bb][ 8 + dd] + b2f((unsigned short)(w2 >> sh)) + bgv;
                float go = gs[0][bb][12 + dd] + gs[1][bb][12 + dd] + b2f((unsigned short)(w3 >> sh)) + bo;
                float si = 1.f / (1.f + __expf(-gi));
                float sf = 1.f / (1.f + __expf(-gf));
                float so = 1.f / (1.f + __expf(-go));
                float tg = 1.f - 2.f / (1.f + __expf(2.f * gg));
                c = sf * c + si * tg;
                float th = 1.f - 2.f / (1.f + __expf(2.f * c));
                float h = so * th;
                // out is never re-read: keep it out of L2 so the release wbl2 stays cheap
                __builtin_nontemporal_store(h, &out[((size_t)bb * TT + t) * HH + gdim]);
                hbuf[((t + 1) & 1) * (BB * HH) + bb * HH + gdim] = f2b(h);
                if (t == len - 1) {
                    __builtin_nontemporal_store(c, &out[(size_t)BB*TT*HH + bb*HH + gdim]);
                    __builtin_nontemporal_store(h, &out[(size_t)BB*TT*HH + (size_t)BB*HH + bb*HH + gdim]);
                }
            }
            __syncthreads();   // all h-slice stores issued & vmcnt-drained
            if (tid == 0) {
                __builtin_amdgcn_fence(__ATOMIC_RELEASE, "agent");   // flush (tiny) dirty set to L3
                __hip_atomic_store(&flags[(size_t)(t + 1) * NWG + wg], 1u,
                                   __ATOMIC_RELAXED, __HIP_MEMORY_SCOPE_AGENT);
            }
        }
    }
}

extern "C" void kernel_launch(void* const* d_in, const int* in_sizes, int n_in,
                              void* d_out, int out_size, void* d_ws, size_t ws_size,
                              hipStream_t stream)
{
    const float* X    = (const float*)d_in[0];
    const int*   lens = (const int*)d_in[1];
    const float* c0   = (const float*)d_in[2];
    const float* h0   = (const float*)d_in[3];
    const float* Wi   = (const float*)d_in[4];
    const float* Wh   = (const float*)d_in[5];
    const float* bias = (const float*)d_in[6];
    float* out = (float*)d_out;

    // ws layout: xp bf16 [B][4H][T] (134.2 MB) | hbuf bf16 [2][B*H] | flags u32 [T+1][NWG]
    unsigned short* xp   = (unsigned short*)d_ws;
    unsigned short* hbuf = xp + (size_t)BB * G4 * TT;
    unsigned int*   flags = (unsigned int*)(hbuf + 2 * BB * HH);

    (void)hipMemsetAsync(flags, 0, sizeof(unsigned int) * (size_t)(TT + 1) * NWG, stream);

    xproj_gemm<<<dim3((BB*TT/64) * (G4/64)), dim3(256), 0, stream>>>(X, Wi, xp);

    const unsigned short* xp_c = xp;
    unsigned short* hbuf_p = hbuf;
    unsigned int* flags_p = flags;
    void* args[9];
    args[0] = (void*)&xp_c;
    args[1] = (void*)&lens;
    args[2] = (void*)&c0;
    args[3] = (void*)&h0;
    args[4] = (void*)&Wh;
    args[5] = (void*)&bias;
    args[6] = (void*)&out;
    args[7] = (void*)&hbuf_p;
    args[8] = (void*)&flags_p;
    (void)hipLaunchCooperativeKernel((void*)lstm_seq, dim3(NWG), dim3(256), args, 0, stream);
}

// Round 4
// 5736.062 us; speedup vs baseline: 3.1269x; 1.8958x over previous
//
#include <hip/hip_runtime.h>

#define BB 32
#define TT 512
#define DD 512
#define HH 1024
#define G4 4096   // 4*H
#define NWG 128
#define BLK 512
#define DPW 8     // h-dims per WG

typedef __bf16 bf16x8 __attribute__((ext_vector_type(8)));
typedef float f32x4 __attribute__((ext_vector_type(4)));
typedef unsigned int u32x4 __attribute__((ext_vector_type(4)));
typedef unsigned short u16x4 __attribute__((ext_vector_type(4)));
typedef unsigned long long u64;
typedef u64 u64x2 __attribute__((ext_vector_type(2)));

__device__ __forceinline__ unsigned short f2b(float f) {
    unsigned u = __builtin_bit_cast(unsigned, f);
    u += 0x7fffu + ((u >> 16) & 1u);
    return (unsigned short)(u >> 16);
}
__device__ __forceinline__ float b2f(unsigned short s) {
    unsigned u = ((unsigned)s) << 16;
    return __builtin_bit_cast(float, u);
}

// ---------- Kernel 1: xp[B][4H][T] = bf16( X[B*T,D] @ Wi[D,4H] ), fp32 accum ----------
__global__ __launch_bounds__(256) void xproj_gemm(const float* __restrict__ X,
                                                  const float* __restrict__ Wi,
                                                  unsigned short* __restrict__ xp)
{
    __shared__ unsigned short As[64][40];   // [m][k]
    __shared__ unsigned short Bs[64][40];   // [n][k] transposed
    const int nb = G4 / 64;
    const int m0 = (blockIdx.x / nb) * 64;
    const int n0 = (blockIdx.x % nb) * 64;
    const int tid = threadIdx.x;
    const int w = tid >> 6;
    const int lane = tid & 63;
    const int q = lane >> 4;
    const int l16 = lane & 15;
    const int wm = (w >> 1) * 32, wn = (w & 1) * 32;

    const int ar = tid >> 2, ac = (tid & 3) * 8;
    const int bk = tid >> 3, bn = (tid & 7) * 8;

    f32x4 acc[2][2] = {};

    for (int k0 = 0; k0 < DD; k0 += 32) {
        const float* ap = X + (size_t)(m0 + ar) * DD + k0 + ac;
        float4 a0 = *(const float4*)ap;
        float4 a1 = *(const float4*)(ap + 4);
        unsigned short* as = &As[ar][ac];
        as[0]=f2b(a0.x); as[1]=f2b(a0.y); as[2]=f2b(a0.z); as[3]=f2b(a0.w);
        as[4]=f2b(a1.x); as[5]=f2b(a1.y); as[6]=f2b(a1.z); as[7]=f2b(a1.w);
        const float* bp = Wi + (size_t)(k0 + bk) * G4 + n0 + bn;
        float4 b0 = *(const float4*)bp;
        float4 b1 = *(const float4*)(bp + 4);
        Bs[bn+0][bk]=f2b(b0.x); Bs[bn+1][bk]=f2b(b0.y); Bs[bn+2][bk]=f2b(b0.z); Bs[bn+3][bk]=f2b(b0.w);
        Bs[bn+4][bk]=f2b(b1.x); Bs[bn+5][bk]=f2b(b1.y); Bs[bn+6][bk]=f2b(b1.z); Bs[bn+7][bk]=f2b(b1.w);
        __syncthreads();
        bf16x8 af0 = *(const bf16x8*)&As[wm + l16][q*8];
        bf16x8 af1 = *(const bf16x8*)&As[wm + 16 + l16][q*8];
        bf16x8 bf0 = *(const bf16x8*)&Bs[wn + l16][q*8];
        bf16x8 bf1 = *(const bf16x8*)&Bs[wn + 16 + l16][q*8];
        acc[0][0] = __builtin_amdgcn_mfma_f32_16x16x32_bf16(af0, bf0, acc[0][0], 0,0,0);
        acc[0][1] = __builtin_amdgcn_mfma_f32_16x16x32_bf16(af0, bf1, acc[0][1], 0,0,0);
        acc[1][0] = __builtin_amdgcn_mfma_f32_16x16x32_bf16(af1, bf0, acc[1][0], 0,0,0);
        acc[1][1] = __builtin_amdgcn_mfma_f32_16x16x32_bf16(af1, bf1, acc[1][1], 0,0,0);
        __syncthreads();
    }
    for (int i = 0; i < 2; i++) for (int j = 0; j < 2; j++) {
        int R = m0 + wm + i*16 + q*4;
        int C = n0 + wn + j*16 + l16;
        int b = R >> 9;
        int t = R & 511;
        u16x4 v;
        v.x = f2b(acc[i][j][0]); v.y = f2b(acc[i][j][1]);
        v.z = f2b(acc[i][j][2]); v.w = f2b(acc[i][j][3]);
        *(u16x4*)(xp + ((size_t)b * G4 + C) * TT + t) = v;
    }
}

// ---------- Kernel 2: persistent LSTM scan, fence-free sc1 dataflow pipeline ----------
// 128 WGs x 512 threads; WG j owns h-dims [8j,8j+8) -> 32 gate columns of Wh in LDS.
// ALL hbuf traffic is relaxed agent-scope (sc1) atomics: bypasses L1/L2 straight to
// the L3 coherence point, so NO acquire/release fences (no buffer_inv / buffer_wbl2,
// which were the 20us/step in round 3). Ordering: __syncthreads() drains vmcnt
// (stores acked at coherence point) before tid0 publishes the step flag.
// Safety: WG reaches step t only after all WGs finished step t-1 => 2-slot hbuf
// double buffer has no WAR hazard.
__global__ __launch_bounds__(BLK, 1) void lstm_seq(
    const unsigned short* __restrict__ xp,      // [B][4H][T] bf16
    const int* __restrict__ lengths,
    const float* __restrict__ c0,
    const float* __restrict__ h0,
    const float* __restrict__ Wh,
    const float* __restrict__ bias,
    float* __restrict__ out,                    // outputs[B,T,H] | c_fin[B,H] | h_fin[B,H]
    unsigned short* __restrict__ hbuf,          // [2][B*H] bf16 (sc1-only access)
    unsigned int* __restrict__ flags)           // [T+1][NWG], zeroed by host memset
{
    __shared__ unsigned short Wt[32][1032];  // [n_local][k]; stride 1032 -> 2-way (free)
    __shared__ float gs[2][32][33];          // [khalf][batch][n_local]
    const int wg = blockIdx.x;
    const int tid = threadIdx.x;
    const int lane = tid & 63;
    const int w = tid >> 6;                  // 0..7
    const int q = lane >> 4, l16 = lane & 15;

    // One-time: stage Wh slice (cols g*H + wg*8 + d, g=0..3,d=0..7) into LDS, [n][k].
    for (int idx = tid; idx < 32 * HH; idx += BLK) {
        int n = idx & 31, k = idx >> 5;
        int col = (n >> 3) * HH + wg * DPW + (n & 7);
        Wt[n][k] = f2b(Wh[(size_t)k * G4 + col]);
    }

    const int bb = tid >> 3, dd = tid & 7;   // valid for tid<256
    const int gdim = wg * DPW + dd;
    float c = 0.f;
    int len = -1;
    float bi = 0.f, bfg = 0.f, bgv = 0.f, bo = 0.f;
    size_t xb0 = 0, xb1 = 0, xb2 = 0, xb3 = 0;
    if (tid < 256) {
        c   = c0[bb * HH + gdim];
        len = lengths[bb];
        bi  = bias[0*HH + gdim];
        bfg = bias[1*HH + gdim];
        bgv = bias[2*HH + gdim];
        bo  = bias[3*HH + gdim];
        xb0 = ((size_t)bb * G4 + 0*HH + gdim) * TT;
        xb1 = ((size_t)bb * G4 + 1*HH + gdim) * TT;
        xb2 = ((size_t)bb * G4 + 2*HH + gdim) * TT;
        xb3 = ((size_t)bb * G4 + 3*HH + gdim) * TT;
    }
    // h0 init: 64 threads store this WG's slice for all batches (u64 = 4 bf16).
    if (tid < 64) {
        int b2 = tid >> 1, j = (tid & 1) * 4;
        const float* hp0 = h0 + (size_t)b2 * HH + wg * DPW + j;
        unsigned lo = (unsigned)f2b(hp0[0]) | ((unsigned)f2b(hp0[1]) << 16);
        unsigned hi = (unsigned)f2b(hp0[2]) | ((unsigned)f2b(hp0[3]) << 16);
        u64 v = (u64)lo | ((u64)hi << 32);
        __hip_atomic_store((u64*)(hbuf + (size_t)b2 * HH + wg * DPW + j), v,
                           __ATOMIC_RELAXED, __HIP_MEMORY_SCOPE_AGENT);
    }
    __syncthreads();                  // vmcnt(0): init stores acked at coherence point
    if (tid == 0)
        __hip_atomic_store(&flags[wg], 1u, __ATOMIC_RELAXED, __HIP_MEMORY_SCOPE_AGENT);

    const int Mt = (w & 1) * 16;      // batch tile
    const int ct = (w >> 1) & 1;      // col tile (16 of 32 cols)
    const int kh = w >> 2;            // K half
    const int kbase = kh * 512;

    for (int t0 = 0; t0 < TT; t0 += 8) {
        // Prefetch 8 steps of x-projection per gate (time-contiguous, nontemporal).
        u32x4 xv0 = {}, xv1 = {}, xv2 = {}, xv3 = {};
        if (tid < 256) {
            xv0 = __builtin_nontemporal_load((const u32x4*)(xp + xb0 + t0));
            xv1 = __builtin_nontemporal_load((const u32x4*)(xp + xb1 + t0));
            xv2 = __builtin_nontemporal_load((const u32x4*)(xp + xb2 + t0));
            xv3 = __builtin_nontemporal_load((const u32x4*)(xp + xb3 + t0));
        }
        #pragma unroll
        for (int dt = 0; dt < 8; ++dt) {
            const int t = t0 + dt;
            // Wait until every producer published h entering step t (sc1 polls, no fence).
            {
                const unsigned* fl = flags + (size_t)t * NWG;
                unsigned mine;
                do {
                    mine = (tid < NWG)
                         ? __hip_atomic_load(&fl[tid], __ATOMIC_RELAXED, __HIP_MEMORY_SCOPE_AGENT)
                         : 1u;
                } while (!__syncthreads_and((int)(mine != 0)));
            }
            const unsigned short* hp = hbuf + (t & 1) * (BB * HH);
            f32x4 acc = {0.f, 0.f, 0.f, 0.f};
            #pragma unroll
            for (int kk = 0; kk < 16; ++kk) {
                int k0 = kbase + kk * 32 + q * 8;
                const u64* ap = (const u64*)(hp + (size_t)(Mt + l16) * HH + k0);
                u64 lo = __hip_atomic_load(ap,     __ATOMIC_RELAXED, __HIP_MEMORY_SCOPE_AGENT);
                u64 hi = __hip_atomic_load(ap + 1, __ATOMIC_RELAXED, __HIP_MEMORY_SCOPE_AGENT);
                u64x2 av = {lo, hi};
                bf16x8 a = __builtin_bit_cast(bf16x8, av);
                bf16x8 b = *(const bf16x8*)&Wt[ct * 16 + l16][k0];
                acc = __builtin_amdgcn_mfma_f32_16x16x32_bf16(a, b, acc, 0, 0, 0);
            }
            #pragma unroll
            for (int r = 0; r < 4; ++r)
                gs[kh][Mt + q*4 + r][ct * 16 + l16] = acc[r];
            __syncthreads();
            float h = 0.f;
            if (tid < 256) {
                const unsigned w0 = ((const unsigned*)&xv0)[dt >> 1];
                const unsigned w1 = ((const unsigned*)&xv1)[dt >> 1];
                const unsigned w2 = ((const unsigned*)&xv2)[dt >> 1];
                const unsigned w3 = ((const unsigned*)&xv3)[dt >> 1];
                const int sh = (dt & 1) * 16;
                float gi = gs[0][bb][ 0 + dd] + gs[1][bb][ 0 + dd] + b2f((unsigned short)(w0 >> sh)) + bi;
                float gf = gs[0][bb][ 8 + dd] + gs[1][bb][ 8 + dd] + b2f((unsigned short)(w1 >> sh)) + bfg;
                float gg = gs[0][bb][16 + dd] + gs[1][bb][16 + dd] + b2f((unsigned short)(w2 >> sh)) + bgv;
                float go = gs[0][bb][24 + dd] + gs[1][bb][24 + dd] + b2f((unsigned short)(w3 >> sh)) + bo;
                float si = 1.f / (1.f + __expf(-gi));
                float sf = 1.f / (1.f + __expf(-gf));
                float so = 1.f / (1.f + __expf(-go));
                float tg = 1.f - 2.f / (1.f + __expf(2.f * gg));
                c = sf * c + si * tg;
                float th = 1.f - 2.f / (1.f + __expf(2.f * c));
                h = so * th;
                // Pack 4 bf16 h values (dims 4-aligned) into u64 via wave shuffles,
                // then one relaxed agent-scope store per quad (bypasses L2 -> L3).
                unsigned v = (unsigned)f2b(h);
                unsigned p1 = __shfl_xor(v, 1);
                unsigned pair = (dd & 1) ? (p1 | (v << 16)) : (v | (p1 << 16));
                unsigned p2 = __shfl_xor(pair, 2);
                u64 quad = (dd & 2) ? ((u64)p2 | ((u64)pair << 32))
                                    : ((u64)pair | ((u64)p2 << 32));
                if ((dd & 3) == 0)
                    __hip_atomic_store((u64*)(hbuf + ((t + 1) & 1) * (BB * HH) + (size_t)bb * HH + gdim),
                                       quad, __ATOMIC_RELAXED, __HIP_MEMORY_SCOPE_AGENT);
            }
            __syncthreads();          // vmcnt(0): h stores acked at coherence point
            if (tid == 0)
                __hip_atomic_store(&flags[(size_t)(t + 1) * NWG + wg], 1u,
                                   __ATOMIC_RELAXED, __HIP_MEMORY_SCOPE_AGENT);
            // out stores AFTER flag publish: HBM write-ack overlaps next step's poll.
            if (tid < 256) {
                __builtin_nontemporal_store(h, &out[((size_t)bb * TT + t) * HH + gdim]);
                if (t == len - 1) {
                    __builtin_nontemporal_store(c, &out[(size_t)BB*TT*HH + bb*HH + gdim]);
                    __builtin_nontemporal_store(h, &out[(size_t)BB*TT*HH + (size_t)BB*HH + bb*HH + gdim]);
                }
            }
        }
    }
}

extern "C" void kernel_launch(void* const* d_in, const int* in_sizes, int n_in,
                              void* d_out, int out_size, void* d_ws, size_t ws_size,
                              hipStream_t stream)
{
    const float* X    = (const float*)d_in[0];
    const int*   lens = (const int*)d_in[1];
    const float* c0   = (const float*)d_in[2];
    const float* h0   = (const float*)d_in[3];
    const float* Wi   = (const float*)d_in[4];
    const float* Wh   = (const float*)d_in[5];
    const float* bias = (const float*)d_in[6];
    float* out = (float*)d_out;

    // ws layout: xp bf16 [B][4H][T] (134.2 MB) | hbuf bf16 [2][B*H] | flags u32 [T+1][NWG]
    unsigned short* xp   = (unsigned short*)d_ws;
    unsigned short* hbuf = xp + (size_t)BB * G4 * TT;
    unsigned int*   flags = (unsigned int*)(hbuf + 2 * BB * HH);

    (void)hipMemsetAsync(flags, 0, sizeof(unsigned int) * (size_t)(TT + 1) * NWG, stream);

    xproj_gemm<<<dim3((BB*TT/64) * (G4/64)), dim3(256), 0, stream>>>(X, Wi, xp);

    const unsigned short* xp_c = xp;
    unsigned short* hbuf_p = hbuf;
    unsigned int* flags_p = flags;
    void* args[9];
    args[0] = (void*)&xp_c;
    args[1] = (void*)&lens;
    args[2] = (void*)&c0;
    args[3] = (void*)&h0;
    args[4] = (void*)&Wh;
    args[5] = (void*)&bias;
    args[6] = (void*)&out;
    args[7] = (void*)&hbuf_p;
    args[8] = (void*)&flags_p;
    (void)hipLaunchCooperativeKernel((void*)lstm_seq, dim3(NWG), dim3(BLK), args, 0, stream);
}

// Round 5
// 3982.798 us; speedup vs baseline: 4.5034x; 1.4402x over previous
//
#include <hip/hip_runtime.h>

#define BB 32
#define TT 512
#define DD 512
#define HH 1024
#define G4 4096   // 4*H
#define NWG 128
#define BLK 512
#define DPW 8     // h-dims per WG
#define HSLOT (BB * HH)   // one h ring slot (elements)

typedef __bf16 bf16x8 __attribute__((ext_vector_type(8)));
typedef float f32x4 __attribute__((ext_vector_type(4)));
typedef unsigned int u32x4 __attribute__((ext_vector_type(4)));
typedef unsigned short u16x4 __attribute__((ext_vector_type(4)));
typedef unsigned long long u64;

__device__ __forceinline__ unsigned short f2b(float f) {
    unsigned u = __builtin_bit_cast(unsigned, f);
    u += 0x7fffu + ((u >> 16) & 1u);
    return (unsigned short)(u >> 16);
}
__device__ __forceinline__ float b2f(unsigned short s) {
    unsigned u = ((unsigned)s) << 16;
    return __builtin_bit_cast(float, u);
}

// ---------- Kernel 1: xp[B][4H][T] = bf16( X[B*T,D] @ Wi[D,4H] ), fp32 accum ----------
__global__ __launch_bounds__(256) void xproj_gemm(const float* __restrict__ X,
                                                  const float* __restrict__ Wi,
                                                  unsigned short* __restrict__ xp)
{
    __shared__ unsigned short As[64][40];   // [m][k]
    __shared__ unsigned short Bs[64][40];   // [n][k] transposed
    const int nb = G4 / 64;
    const int m0 = (blockIdx.x / nb) * 64;
    const int n0 = (blockIdx.x % nb) * 64;
    const int tid = threadIdx.x;
    const int w = tid >> 6;
    const int lane = tid & 63;
    const int q = lane >> 4;
    const int l16 = lane & 15;
    const int wm = (w >> 1) * 32, wn = (w & 1) * 32;

    const int ar = tid >> 2, ac = (tid & 3) * 8;
    const int bk = tid >> 3, bn = (tid & 7) * 8;

    f32x4 acc[2][2] = {};

    for (int k0 = 0; k0 < DD; k0 += 32) {
        const float* ap = X + (size_t)(m0 + ar) * DD + k0 + ac;
        float4 a0 = *(const float4*)ap;
        float4 a1 = *(const float4*)(ap + 4);
        unsigned short* as = &As[ar][ac];
        as[0]=f2b(a0.x); as[1]=f2b(a0.y); as[2]=f2b(a0.z); as[3]=f2b(a0.w);
        as[4]=f2b(a1.x); as[5]=f2b(a1.y); as[6]=f2b(a1.z); as[7]=f2b(a1.w);
        const float* bp = Wi + (size_t)(k0 + bk) * G4 + n0 + bn;
        float4 b0 = *(const float4*)bp;
        float4 b1 = *(const float4*)(bp + 4);
        Bs[bn+0][bk]=f2b(b0.x); Bs[bn+1][bk]=f2b(b0.y); Bs[bn+2][bk]=f2b(b0.z); Bs[bn+3][bk]=f2b(b0.w);
        Bs[bn+4][bk]=f2b(b1.x); Bs[bn+5][bk]=f2b(b1.y); Bs[bn+6][bk]=f2b(b1.z); Bs[bn+7][bk]=f2b(b1.w);
        __syncthreads();
        bf16x8 af0 = *(const bf16x8*)&As[wm + l16][q*8];
        bf16x8 af1 = *(const bf16x8*)&As[wm + 16 + l16][q*8];
        bf16x8 bf0 = *(const bf16x8*)&Bs[wn + l16][q*8];
        bf16x8 bf1 = *(const bf16x8*)&Bs[wn + 16 + l16][q*8];
        acc[0][0] = __builtin_amdgcn_mfma_f32_16x16x32_bf16(af0, bf0, acc[0][0], 0,0,0);
        acc[0][1] = __builtin_amdgcn_mfma_f32_16x16x32_bf16(af0, bf1, acc[0][1], 0,0,0);
        acc[1][0] = __builtin_amdgcn_mfma_f32_16x16x32_bf16(af1, bf0, acc[1][0], 0,0,0);
        acc[1][1] = __builtin_amdgcn_mfma_f32_16x16x32_bf16(af1, bf1, acc[1][1], 0,0,0);
        __syncthreads();
    }
    for (int i = 0; i < 2; i++) for (int j = 0; j < 2; j++) {
        int R = m0 + wm + i*16 + q*4;
        int C = n0 + wn + j*16 + l16;
        int b = R >> 9;
        int t = R & 511;
        u16x4 v;
        v.x = f2b(acc[i][j][0]); v.y = f2b(acc[i][j][1]);
        v.z = f2b(acc[i][j][2]); v.w = f2b(acc[i][j][3]);
        *(u16x4*)(xp + ((size_t)b * G4 + C) * TT + t) = v;
    }
}

// ---------- Kernel 2: persistent LSTM scan, ring-buffer dataflow pipeline ----------
// 128 WGs x 512 threads; WG j owns h-dims [8j,8j+8) -> 32 gate columns of Wh in LDS.
// h state lives in a NON-REUSED ring of T+1 slots:
//   - producers write slot t+1 with relaxed agent-scope (sc1) u64 stores -> L3
//     coherence point; __syncthreads() drains vmcnt (acks) before the flag store.
//   - consumers read slot t with PLAIN cached vector loads. Safe because every
//     ring address is written exactly once, strictly before (flag protocol) any
//     read of it, and kernel-start acquire invalidated pre-kernel L1/L2 state;
//     so no cache can hold a stale copy. Plain loads coalesce to full 64B lines
//     (4 q-lanes per row) and hit per-XCD L2 after the first WG's miss — this
//     removes the ~2M/step L3 transactions that round-4's sc1 loads caused.
// No fences anywhere in the loop.
__global__ __launch_bounds__(BLK, 1) void lstm_seq(
    const unsigned short* __restrict__ xp,      // [B][4H][T] bf16
    const int* __restrict__ lengths,
    const float* __restrict__ c0,
    const float* __restrict__ h0,
    const float* __restrict__ Wh,
    const float* __restrict__ bias,
    float* __restrict__ out,                    // outputs[B,T,H] | c_fin[B,H] | h_fin[B,H]
    unsigned short* __restrict__ hbuf,          // [T+1][B*H] bf16 ring
    unsigned int* __restrict__ flags)           // [T+1][NWG], zeroed by host memset
{
    __shared__ unsigned short Wt[32][1032];  // [n_local][k]; stride 1032 -> 2-way (free)
    __shared__ float gs[2][32][33];          // [khalf][batch][n_local]
    const int wg = blockIdx.x;
    const int tid = threadIdx.x;
    const int lane = tid & 63;
    const int w = tid >> 6;                  // 0..7
    const int q = lane >> 4, l16 = lane & 15;

    // One-time: stage Wh slice (cols g*H + wg*8 + d, g=0..3,d=0..7) into LDS, [n][k].
    for (int idx = tid; idx < 32 * HH; idx += BLK) {
        int n = idx & 31, k = idx >> 5;
        int col = (n >> 3) * HH + wg * DPW + (n & 7);
        Wt[n][k] = f2b(Wh[(size_t)k * G4 + col]);
    }

    const int bb = tid >> 3, dd = tid & 7;   // valid for tid<256
    const int gdim = wg * DPW + dd;
    float c = 0.f;
    int len = -1;
    float bi = 0.f, bfg = 0.f, bgv = 0.f, bo = 0.f;
    size_t xb0 = 0, xb1 = 0, xb2 = 0, xb3 = 0;
    if (tid < 256) {
        c   = c0[bb * HH + gdim];
        len = lengths[bb];
        bi  = bias[0*HH + gdim];
        bfg = bias[1*HH + gdim];
        bgv = bias[2*HH + gdim];
        bo  = bias[3*HH + gdim];
        xb0 = ((size_t)bb * G4 + 0*HH + gdim) * TT;
        xb1 = ((size_t)bb * G4 + 1*HH + gdim) * TT;
        xb2 = ((size_t)bb * G4 + 2*HH + gdim) * TT;
        xb3 = ((size_t)bb * G4 + 3*HH + gdim) * TT;
    }
    // h0 init: 64 threads store this WG's slice for all batches into slot 0.
    if (tid < 64) {
        int b2 = tid >> 1, j = (tid & 1) * 4;
        const float* hp0 = h0 + (size_t)b2 * HH + wg * DPW + j;
        unsigned lo = (unsigned)f2b(hp0[0]) | ((unsigned)f2b(hp0[1]) << 16);
        unsigned hi = (unsigned)f2b(hp0[2]) | ((unsigned)f2b(hp0[3]) << 16);
        u64 v = (u64)lo | ((u64)hi << 32);
        __hip_atomic_store((u64*)(hbuf + (size_t)b2 * HH + wg * DPW + j), v,
                           __ATOMIC_RELAXED, __HIP_MEMORY_SCOPE_AGENT);
    }
    __syncthreads();                  // vmcnt(0): init stores acked at coherence point
    if (tid == 0)
        __hip_atomic_store(&flags[wg], 1u, __ATOMIC_RELAXED, __HIP_MEMORY_SCOPE_AGENT);

    const int Mt = (w & 1) * 16;      // batch tile
    const int ct = (w >> 1) & 1;      // col tile (16 of 32 cols)
    const int kh = w >> 2;            // K half
    const int kbase = kh * 512;

    for (int t0 = 0; t0 < TT; t0 += 8) {
        // Prefetch 8 steps of x-projection per gate (time-contiguous, nontemporal).
        u32x4 xv0 = {}, xv1 = {}, xv2 = {}, xv3 = {};
        if (tid < 256) {
            xv0 = __builtin_nontemporal_load((const u32x4*)(xp + xb0 + t0));
            xv1 = __builtin_nontemporal_load((const u32x4*)(xp + xb1 + t0));
            xv2 = __builtin_nontemporal_load((const u32x4*)(xp + xb2 + t0));
            xv3 = __builtin_nontemporal_load((const u32x4*)(xp + xb3 + t0));
        }
        #pragma unroll
        for (int dt = 0; dt < 8; ++dt) {
            const int t = t0 + dt;
            // Wait until every producer published h entering step t (sc1 polls).
            {
                const unsigned* fl = flags + (size_t)t * NWG;
                unsigned mine;
                do {
                    mine = (tid < NWG)
                         ? __hip_atomic_load(&fl[tid], __ATOMIC_RELAXED, __HIP_MEMORY_SCOPE_AGENT)
                         : 1u;
                } while (!__syncthreads_and((int)(mine != 0)));
            }
            const unsigned short* hp = hbuf + (size_t)t * HSLOT;   // ring slot t
            f32x4 acc = {0.f, 0.f, 0.f, 0.f};
            #pragma unroll
            for (int kk = 0; kk < 16; ++kk) {
                int k0 = kbase + kk * 32 + q * 8;
                bf16x8 a = *(const bf16x8*)(hp + (size_t)(Mt + l16) * HH + k0);  // plain cached
                bf16x8 b = *(const bf16x8*)&Wt[ct * 16 + l16][k0];
                acc = __builtin_amdgcn_mfma_f32_16x16x32_bf16(a, b, acc, 0, 0, 0);
            }
            #pragma unroll
            for (int r = 0; r < 4; ++r)
                gs[kh][Mt + q*4 + r][ct * 16 + l16] = acc[r];
            __syncthreads();
            float h = 0.f;
            if (tid < 256) {
                const unsigned w0 = ((const unsigned*)&xv0)[dt >> 1];
                const unsigned w1 = ((const unsigned*)&xv1)[dt >> 1];
                const unsigned w2 = ((const unsigned*)&xv2)[dt >> 1];
                const unsigned w3 = ((const unsigned*)&xv3)[dt >> 1];
                const int sh = (dt & 1) * 16;
                float gi = gs[0][bb][ 0 + dd] + gs[1][bb][ 0 + dd] + b2f((unsigned short)(w0 >> sh)) + bi;
                float gf = gs[0][bb][ 8 + dd] + gs[1][bb][ 8 + dd] + b2f((unsigned short)(w1 >> sh)) + bfg;
                float gg = gs[0][bb][16 + dd] + gs[1][bb][16 + dd] + b2f((unsigned short)(w2 >> sh)) + bgv;
                float go = gs[0][bb][24 + dd] + gs[1][bb][24 + dd] + b2f((unsigned short)(w3 >> sh)) + bo;
                float si = 1.f / (1.f + __expf(-gi));
                float sf = 1.f / (1.f + __expf(-gf));
                float so = 1.f / (1.f + __expf(-go));
                float tg = 1.f - 2.f / (1.f + __expf(2.f * gg));
                c = sf * c + si * tg;
                float th = 1.f - 2.f / (1.f + __expf(2.f * c));
                h = so * th;
                // Pack 4 bf16 h values (dims 4-aligned) into u64 via wave shuffles,
                // one relaxed agent-scope store per quad into ring slot t+1.
                unsigned v = (unsigned)f2b(h);
                unsigned p1 = __shfl_xor(v, 1);
                unsigned pair = (dd & 1) ? (p1 | (v << 16)) : (v | (p1 << 16));
                unsigned p2 = __shfl_xor(pair, 2);
                u64 quad = (dd & 2) ? ((u64)p2 | ((u64)pair << 32))
                                    : ((u64)pair | ((u64)p2 << 32));
                if ((dd & 3) == 0)
                    __hip_atomic_store((u64*)(hbuf + (size_t)(t + 1) * HSLOT + (size_t)bb * HH + gdim),
                                       quad, __ATOMIC_RELAXED, __HIP_MEMORY_SCOPE_AGENT);
            }
            __syncthreads();          // vmcnt(0): h stores acked at coherence point
            if (tid == 0)
                __hip_atomic_store(&flags[(size_t)(t + 1) * NWG + wg], 1u,
                                   __ATOMIC_RELAXED, __HIP_MEMORY_SCOPE_AGENT);
            // out stores AFTER flag publish: HBM write-ack overlaps next step's poll.
            if (tid < 256) {
                __builtin_nontemporal_store(h, &out[((size_t)bb * TT + t) * HH + gdim]);
                if (t == len - 1) {
                    __builtin_nontemporal_store(c, &out[(size_t)BB*TT*HH + bb*HH + gdim]);
                    __builtin_nontemporal_store(h, &out[(size_t)BB*TT*HH + (size_t)BB*HH + bb*HH + gdim]);
                }
            }
        }
    }
}

extern "C" void kernel_launch(void* const* d_in, const int* in_sizes, int n_in,
                              void* d_out, int out_size, void* d_ws, size_t ws_size,
                              hipStream_t stream)
{
    const float* X    = (const float*)d_in[0];
    const int*   lens = (const int*)d_in[1];
    const float* c0   = (const float*)d_in[2];
    const float* h0   = (const float*)d_in[3];
    const float* Wi   = (const float*)d_in[4];
    const float* Wh   = (const float*)d_in[5];
    const float* bias = (const float*)d_in[6];
    float* out = (float*)d_out;

    // ws layout: xp bf16 [B][4H][T] (134.2 MB) | hbuf ring bf16 [T+1][B*H] (33.6 MB)
    //          | flags u32 [T+1][NWG] (0.26 MB)
    unsigned short* xp   = (unsigned short*)d_ws;
    unsigned short* hbuf = xp + (size_t)BB * G4 * TT;
    unsigned int*   flags = (unsigned int*)(hbuf + (size_t)(TT + 1) * HSLOT);

    (void)hipMemsetAsync(flags, 0, sizeof(unsigned int) * (size_t)(TT + 1) * NWG, stream);

    xproj_gemm<<<dim3((BB*TT/64) * (G4/64)), dim3(256), 0, stream>>>(X, Wi, xp);

    const unsigned short* xp_c = xp;
    unsigned short* hbuf_p = hbuf;
    unsigned int* flags_p = flags;
    void* args[9];
    args[0] = (void*)&xp_c;
    args[1] = (void*)&lens;
    args[2] = (void*)&c0;
    args[3] = (void*)&h0;
    args[4] = (void*)&Wh;
    args[5] = (void*)&bias;
    args[6] = (void*)&out;
    args[7] = (void*)&hbuf_p;
    args[8] = (void*)&flags_p;
    (void)hipLaunchCooperativeKernel((void*)lstm_seq, dim3(NWG), dim3(BLK), args, 0, stream);
}

// Round 6
// 3642.406 us; speedup vs baseline: 4.9243x; 1.0935x over previous
//
#include <hip/hip_runtime.h>

#define BB 32
#define TT 512
#define DD 512
#define HH 1024
#define G4 4096   // 4*H
#define NWG 64
#define BLK 512
#define DPW 16    // h-dims per WG
#define HSLOT (BB * HH)   // one h ring slot (elements)

typedef __bf16 bf16x8 __attribute__((ext_vector_type(8)));
typedef float f32x4 __attribute__((ext_vector_type(4)));
typedef unsigned int u32x4 __attribute__((ext_vector_type(4)));
typedef unsigned short u16x4 __attribute__((ext_vector_type(4)));
typedef unsigned short u16x8 __attribute__((ext_vector_type(8)));
typedef unsigned long long u64;

__device__ __forceinline__ unsigned short f2b(float f) {
    unsigned u = __builtin_bit_cast(unsigned, f);
    u += 0x7fffu + ((u >> 16) & 1u);
    return (unsigned short)(u >> 16);
}
__device__ __forceinline__ float b2f(unsigned short s) {
    unsigned u = ((unsigned)s) << 16;
    return __builtin_bit_cast(float, u);
}

// ---------- Kernel 1: xp = bf16( X[B*T,D] @ Wi[D,4H] ), fp32 accum ----------
// Output layout: xp[b][hdim][t/8][gate][t&7]  -> one thread's 4 gates x 8 steps
// are a single contiguous 64B chunk (fixes the 4x overfetch of round 5).
__global__ __launch_bounds__(256) void xproj_gemm(const float* __restrict__ X,
                                                  const float* __restrict__ Wi,
                                                  unsigned short* __restrict__ xp)
{
    __shared__ unsigned short As[64][40];   // [m][k]
    __shared__ unsigned short Bs[64][40];   // [n][k] transposed
    const int nb = G4 / 64;
    const int m0 = (blockIdx.x / nb) * 64;
    const int n0 = (blockIdx.x % nb) * 64;
    const int tid = threadIdx.x;
    const int w = tid >> 6;
    const int lane = tid & 63;
    const int q = lane >> 4;
    const int l16 = lane & 15;
    const int wm = (w >> 1) * 32, wn = (w & 1) * 32;

    const int ar = tid >> 2, ac = (tid & 3) * 8;
    const int bk = tid >> 3, bn = (tid & 7) * 8;

    f32x4 acc[2][2] = {};

    for (int k0 = 0; k0 < DD; k0 += 32) {
        const float* ap = X + (size_t)(m0 + ar) * DD + k0 + ac;
        float4 a0 = *(const float4*)ap;
        float4 a1 = *(const float4*)(ap + 4);
        unsigned short* as = &As[ar][ac];
        as[0]=f2b(a0.x); as[1]=f2b(a0.y); as[2]=f2b(a0.z); as[3]=f2b(a0.w);
        as[4]=f2b(a1.x); as[5]=f2b(a1.y); as[6]=f2b(a1.z); as[7]=f2b(a1.w);
        const float* bp = Wi + (size_t)(k0 + bk) * G4 + n0 + bn;
        float4 b0 = *(const float4*)bp;
        float4 b1 = *(const float4*)(bp + 4);
        Bs[bn+0][bk]=f2b(b0.x); Bs[bn+1][bk]=f2b(b0.y); Bs[bn+2][bk]=f2b(b0.z); Bs[bn+3][bk]=f2b(b0.w);
        Bs[bn+4][bk]=f2b(b1.x); Bs[bn+5][bk]=f2b(b1.y); Bs[bn+6][bk]=f2b(b1.z); Bs[bn+7][bk]=f2b(b1.w);
        __syncthreads();
        bf16x8 af0 = *(const bf16x8*)&As[wm + l16][q*8];
        bf16x8 af1 = *(const bf16x8*)&As[wm + 16 + l16][q*8];
        bf16x8 bf0 = *(const bf16x8*)&Bs[wn + l16][q*8];
        bf16x8 bf1 = *(const bf16x8*)&Bs[wn + 16 + l16][q*8];
        acc[0][0] = __builtin_amdgcn_mfma_f32_16x16x32_bf16(af0, bf0, acc[0][0], 0,0,0);
        acc[0][1] = __builtin_amdgcn_mfma_f32_16x16x32_bf16(af0, bf1, acc[0][1], 0,0,0);
        acc[1][0] = __builtin_amdgcn_mfma_f32_16x16x32_bf16(af1, bf0, acc[1][0], 0,0,0);
        acc[1][1] = __builtin_amdgcn_mfma_f32_16x16x32_bf16(af1, bf1, acc[1][1], 0,0,0);
        __syncthreads();
    }
    // C/D: col=lane&15, row=quad*4+reg. Rows R..R+3 = 4 consecutive t in one b.
    for (int i = 0; i < 2; i++) for (int j = 0; j < 2; j++) {
        int R = m0 + wm + i*16 + q*4;
        int C = n0 + wn + j*16 + l16;
        int b = R >> 9;
        int t = R & 511;
        int g = C >> 10;
        int hd = C & (HH - 1);
        u16x4 v;
        v.x = f2b(acc[i][j][0]); v.y = f2b(acc[i][j][1]);
        v.z = f2b(acc[i][j][2]); v.w = f2b(acc[i][j][3]);
        size_t off = (((size_t)(b * HH + hd) * (TT/8) + (t >> 3)) * 4 + g) * 8 + (t & 7);
        *(u16x4*)(xp + off) = v;
    }
}

// ---------- Kernel 2: persistent LSTM scan, counter-protocol ring pipeline ----------
// 64 WGs x 512 threads; WG j owns h-dims [16j,16j+16) -> 64 gate columns of Wh,
// held ENTIRELY IN REGISTERS (32 B-frags/wave = 128 VGPR) — no per-step LDS/weight
// traffic. h ring: T+1 non-reused slots; producers sc1 u64 stores, consumers plain
// cached loads (safe: each address written once, strictly before any read).
// Sync: producers atomic_add ctr[t+1] (one RMW per WG); only tid0 polls ctr[t],
// one barrier releases the WG. out values are register-buffered 8 steps and
// flushed so HBM store-acks drain during the next poll wait.
__global__ __launch_bounds__(BLK, 1) void lstm_seq(
    const unsigned short* __restrict__ xp,      // [B][H][T/8][4][8] bf16
    const int* __restrict__ lengths,
    const float* __restrict__ c0,
    const float* __restrict__ h0,
    const float* __restrict__ Wh,
    const float* __restrict__ bias,
    float* __restrict__ out,                    // outputs[B,T,H] | c_fin[B,H] | h_fin[B,H]
    unsigned short* __restrict__ hbuf,          // [T+1][B*H] bf16 ring
    unsigned int* __restrict__ ctr)             // [T+1] counters, zeroed by host memset
{
    __shared__ float gs[2][32][65];          // [khalf][batch][n_local]
    const int wg = blockIdx.x;
    const int tid = threadIdx.x;
    const int lane = tid & 63;
    const int w = tid >> 6;                  // 0..7
    const int q = lane >> 4, l16 = lane & 15;

    const int Mt = (w & 1) * 16;             // batch tile
    const int kh = (w >> 1) & 1;             // K half
    const int cp = w >> 2;                   // col-tile pair: ct = cp*2 + cc
    const int kbase = kh * 512;

    // ---- one-time: load this wave's 32 Wh B-fragments into registers ----
    // frag(kk,cc): lane(q,l16) holds B[k = kbase+kk*32+q*8+e][col],
    // col = (cp*2+cc)*H + wg*16 + l16  (gate = ct, dim = l16)
    bf16x8 breg[16][2];
    #pragma unroll
    for (int kk = 0; kk < 16; ++kk) {
        #pragma unroll
        for (int cc = 0; cc < 2; ++cc) {
            const int col = (cp*2 + cc) * HH + wg * DPW + l16;
            const int kb = kbase + kk*32 + q*8;
            u16x8 tv;
            #pragma unroll
            for (int e = 0; e < 8; ++e)
                tv[e] = f2b(Wh[(size_t)(kb + e) * G4 + col]);
            breg[kk][cc] = __builtin_bit_cast(bf16x8, tv);
        }
    }

    const int bb = tid >> 4, dd = tid & 15;  // all 512 threads do pointwise
    const int gdim = wg * DPW + dd;
    float c   = c0[bb * HH + gdim];
    const int len = lengths[bb];
    const float bi  = bias[0*HH + gdim];
    const float bfg = bias[1*HH + gdim];
    const float bgv = bias[2*HH + gdim];
    const float bo  = bias[3*HH + gdim];
    const size_t xrow = ((size_t)bb * HH + gdim) * (TT/8) * 32;

    // h0 init: 128 threads store this WG's slice (32 b x 16 dims = 128 quads).
    if (tid < 128) {
        int b2 = tid >> 2, j = (tid & 3) * 4;
        const float* hp0 = h0 + (size_t)b2 * HH + wg * DPW + j;
        unsigned lo = (unsigned)f2b(hp0[0]) | ((unsigned)f2b(hp0[1]) << 16);
        unsigned hi = (unsigned)f2b(hp0[2]) | ((unsigned)f2b(hp0[3]) << 16);
        u64 v = (u64)lo | ((u64)hi << 32);
        __hip_atomic_store((u64*)(hbuf + (size_t)b2 * HH + wg * DPW + j), v,
                           __ATOMIC_RELAXED, __HIP_MEMORY_SCOPE_AGENT);
    }
    __syncthreads();                  // vmcnt(0): init stores acked at coherence point
    if (tid == 0)
        (void)__hip_atomic_fetch_add(&ctr[0], 1u, __ATOMIC_RELAXED, __HIP_MEMORY_SCOPE_AGENT);

    for (int t0 = 0; t0 < TT; t0 += 8) {
        // Prefetch 8 steps x 4 gates of x-projection: one contiguous 64B chunk.
        const unsigned short* xc = xp + xrow + (size_t)(t0 >> 3) * 32;
        u32x4 xq0 = __builtin_nontemporal_load((const u32x4*)(xc + 0));
        u32x4 xq1 = __builtin_nontemporal_load((const u32x4*)(xc + 8));
        u32x4 xq2 = __builtin_nontemporal_load((const u32x4*)(xc + 16));
        u32x4 xq3 = __builtin_nontemporal_load((const u32x4*)(xc + 24));
        float hreg[8];
        #pragma unroll
        for (int dt = 0; dt < 8; ++dt) {
            const int t = t0 + dt;
            // Wait until all 64 producers published h slot t (single-lane poll).
            if (tid == 0) {
                while (__hip_atomic_load(&ctr[t], __ATOMIC_RELAXED,
                                         __HIP_MEMORY_SCOPE_AGENT) < (unsigned)NWG) {}
            }
            __syncthreads();
            const unsigned short* ha = hbuf + (size_t)t * HSLOT
                                     + (size_t)(Mt + l16) * HH + kbase + q*8;
            f32x4 acc0 = {0.f,0.f,0.f,0.f}, acc1 = {0.f,0.f,0.f,0.f};
            #pragma unroll
            for (int kk = 0; kk < 16; ++kk) {
                bf16x8 a = *(const bf16x8*)(ha + kk*32);   // plain cached
                acc0 = __builtin_amdgcn_mfma_f32_16x16x32_bf16(a, breg[kk][0], acc0, 0,0,0);
                acc1 = __builtin_amdgcn_mfma_f32_16x16x32_bf16(a, breg[kk][1], acc1, 0,0,0);
            }
            #pragma unroll
            for (int r = 0; r < 4; ++r) {
                gs[kh][Mt + q*4 + r][(cp*2+0)*16 + l16] = acc0[r];
                gs[kh][Mt + q*4 + r][(cp*2+1)*16 + l16] = acc1[r];
            }
            __syncthreads();
            const int wi = dt >> 1, sh = (dt & 1) * 16;
            float gi = gs[0][bb][ 0 + dd] + gs[1][bb][ 0 + dd] + b2f((unsigned short)(xq0[wi] >> sh)) + bi;
            float gf = gs[0][bb][16 + dd] + gs[1][bb][16 + dd] + b2f((unsigned short)(xq1[wi] >> sh)) + bfg;
            float gg = gs[0][bb][32 + dd] + gs[1][bb][32 + dd] + b2f((unsigned short)(xq2[wi] >> sh)) + bgv;
            float go = gs[0][bb][48 + dd] + gs[1][bb][48 + dd] + b2f((unsigned short)(xq3[wi] >> sh)) + bo;
            float si = 1.f / (1.f + __expf(-gi));
            float sf = 1.f / (1.f + __expf(-gf));
            float so = 1.f / (1.f + __expf(-go));
            float tg = 1.f - 2.f / (1.f + __expf(2.f * gg));
            c = sf * c + si * tg;
            float th = 1.f - 2.f / (1.f + __expf(2.f * c));
            float h = so * th;
            hreg[dt] = h;
            // Pack 4 bf16 h (dims 4-aligned) into u64 via shuffles; one sc1 store/quad.
            unsigned v = (unsigned)f2b(h);
            unsigned p1 = __shfl_xor(v, 1);
            unsigned pair = (dd & 1) ? (p1 | (v << 16)) : (v | (p1 << 16));
            unsigned p2 = __shfl_xor(pair, 2);
            u64 quad = (dd & 2) ? ((u64)p2 | ((u64)pair << 32))
                                : ((u64)pair | ((u64)p2 << 32));
            if ((dd & 3) == 0)
                __hip_atomic_store((u64*)(hbuf + (size_t)(t + 1) * HSLOT + (size_t)bb * HH + gdim),
                                   quad, __ATOMIC_RELAXED, __HIP_MEMORY_SCOPE_AGENT);
            __syncthreads();          // vmcnt(0): h stores acked at coherence point
            if (tid == 0)
                (void)__hip_atomic_fetch_add(&ctr[t + 1], 1u, __ATOMIC_RELAXED,
                                             __HIP_MEMORY_SCOPE_AGENT);
            if (t == len - 1) {       // rare: final states
                __builtin_nontemporal_store(c, &out[(size_t)BB*TT*HH + bb*HH + gdim]);
                __builtin_nontemporal_store(h, &out[(size_t)BB*TT*HH + (size_t)BB*HH + bb*HH + gdim]);
            }
        }
        // Flush 8 buffered h outputs; acks drain during next block's poll wait.
        #pragma unroll
        for (int j = 0; j < 8; ++j)
            __builtin_nontemporal_store(hreg[j], &out[((size_t)bb * TT + t0 + j) * HH + gdim]);
    }
}

extern "C" void kernel_launch(void* const* d_in, const int* in_sizes, int n_in,
                              void* d_out, int out_size, void* d_ws, size_t ws_size,
                              hipStream_t stream)
{
    const float* X    = (const float*)d_in[0];
    const int*   lens = (const int*)d_in[1];
    const float* c0   = (const float*)d_in[2];
    const float* h0   = (const float*)d_in[3];
    const float* Wi   = (const float*)d_in[4];
    const float* Wh   = (const float*)d_in[5];
    const float* bias = (const float*)d_in[6];
    float* out = (float*)d_out;

    // ws layout: xp bf16 [B][H][T/8][4][8] (134.2 MB) | hbuf ring bf16 [T+1][B*H]
    //            (33.6 MB) | ctr u32 [T+1]
    unsigned short* xp   = (unsigned short*)d_ws;
    unsigned short* hbuf = xp + (size_t)BB * HH * TT * 4;
    unsigned int*   ctr  = (unsigned int*)(hbuf + (size_t)(TT + 1) * HSLOT);

    (void)hipMemsetAsync(ctr, 0, sizeof(unsigned int) * (size_t)(TT + 1), stream);

    xproj_gemm<<<dim3((BB*TT/64) * (G4/64)), dim3(256), 0, stream>>>(X, Wi, xp);

    const unsigned short* xp_c = xp;
    unsigned short* hbuf_p = hbuf;
    unsigned int* ctr_p = ctr;
    void* args[9];
    args[0] = (void*)&xp_c;
    args[1] = (void*)&lens;
    args[2] = (void*)&c0;
    args[3] = (void*)&h0;
    args[4] = (void*)&Wh;
    args[5] = (void*)&bias;
    args[6] = (void*)&out;
    args[7] = (void*)&hbuf_p;
    args[8] = (void*)&ctr_p;
    (void)hipLaunchCooperativeKernel((void*)lstm_seq, dim3(NWG), dim3(BLK), args, 0, stream);
}